// Round 8
// baseline (264.842 us; speedup 1.0000x reference)
//
#include <hip/hip_runtime.h>

#define NN 100000
#define NE 1600000
#define NG 256

#define BSH 8                 // bucket = dst >> 8  (256 nodes/bucket)
#define NPB 256               // nodes per bucket
#define NBKT ((NN + NPB - 1) / NPB)   // 391
#define STRIDE 4608           // fixed bucket region (mean 4096, +8 sigma)
#define TILE 8192
#define NB_P1 ((NE + TILE - 1) / TILE) // 196
#define NB_CONV (((size_t)NN * 8 + 511) / 512)   // 1563

__device__ __forceinline__ unsigned short f2bf(float x) {
    unsigned int u = __float_as_uint(x);
    u += 0x7FFFu + ((u >> 16) & 1u);   // round-to-nearest-even
    return (unsigned short)(u >> 16);
}
__device__ __forceinline__ float2 bf2x2(unsigned int v) {
    float2 r;
    r.x = __uint_as_float(v << 16);
    r.y = __uint_as_float(v & 0xFFFF0000u);
    return r;
}
__device__ __forceinline__ unsigned int bfpack(float x, float y) {
    return (unsigned int)f2bf(x) | ((unsigned int)f2bf(y) << 16);
}

// ---- partition edges into fixed-stride bucket regions (packed: src | local<<17) ----
// Multisplit: reorder tile in LDS so global writes are dense & coalesced.
__global__ __launch_bounds__(1024) void part_kernel(const int* __restrict__ src,
                                                    const int* __restrict__ dst,
                                                    int* __restrict__ bkt_cur,
                                                    int* __restrict__ epack) {
    __shared__ int hist[512];                 // padded to 512 for scan (NBKT=391)
    __shared__ int scan0[512];
    __shared__ int cur[NBKT];                 // LDS write cursors
    __shared__ int gbase[NBKT];               // global_base - lds_exclusive_offset
    __shared__ int stage[TILE];               // 32 KB staged packed edges
    __shared__ unsigned short sb[TILE];       // 16 KB bucket id per staged slot
    int tid = threadIdx.x;
    int e0 = blockIdx.x * TILE;
    int e1 = min(e0 + TILE, NE);
    int n = e1 - e0;

    for (int i = tid; i < 512; i += 1024) hist[i] = 0;
    __syncthreads();

    // read edges once into registers (non-temporal: pure stream), histogram dst buckets
    int d_[8], s_[8];
#pragma unroll
    for (int k = 0; k < 8; ++k) {
        int e = e0 + tid + k * 1024;
        if (e < e1) {
            d_[k] = __builtin_nontemporal_load(&dst[e]);
            s_[k] = __builtin_nontemporal_load(&src[e]);
            atomicAdd(&hist[d_[k] >> BSH], 1);
        }
    }
    __syncthreads();

    // inclusive Hillis-Steele scan over 512 slots
    if (tid < 512) scan0[tid] = hist[tid];
    __syncthreads();
    for (int off = 1; off < 512; off <<= 1) {
        int t = (tid < 512 && tid >= off) ? scan0[tid - off] : 0;
        __syncthreads();
        if (tid < 512) scan0[tid] += t;
        __syncthreads();
    }
    if (tid < NBKT) {
        int h = hist[tid];
        int ex = scan0[tid] - h;               // exclusive offset in LDS
        cur[tid] = ex;
        gbase[tid] = tid * STRIDE + (h ? atomicAdd(&bkt_cur[tid], h) : 0) - ex;
    }
    __syncthreads();

    // scatter into LDS (cheap), record bucket id
#pragma unroll
    for (int k = 0; k < 8; ++k) {
        int e = e0 + tid + k * 1024;
        if (e < e1) {
            int d = d_[k];
            int bk = d >> BSH;
            int p = atomicAdd(&cur[bk], 1);
            stage[p] = s_[k] | ((d & (NPB - 1)) << 17);
            sb[p] = (unsigned short)bk;
        }
    }
    __syncthreads();

    // dense coalesced flush: per-bucket runs are contiguous in both LDS and global
    for (int j = tid; j < n; j += 1024) {
        int bk = sb[j];
        int a = gbase[bk] + j;
        if (a < (bk + 1) * STRIDE)             // overflow guard (8-sigma; never expected)
            epack[a] = stage[j];
    }
}

// ---- per-bucket fine CSR build (LDS only): row_beg/row_deg + deg_inv + col ----
// epack reads cached (18 KB region re-read in 2nd pass); col writes non-temporal.
__global__ __launch_bounds__(512) void build_kernel(const int* __restrict__ epack,
                                                    const int* __restrict__ bkt_cur,
                                                    int* __restrict__ row_beg,
                                                    int* __restrict__ row_deg,
                                                    int* __restrict__ col,
                                                    float* __restrict__ deg_inv) {
    __shared__ int cnt[NPB];
    __shared__ int ts[NPB];
    int b = blockIdx.x;
    int tid = threadIdx.x;
    int ebase = b * STRIDE;
    int eend = ebase + min(bkt_cur[b], STRIDE);
    int nbase = b << BSH;
    if (tid < NPB) cnt[tid] = 0;
    __syncthreads();
    for (int e = ebase + tid; e < eend; e += 512)
        atomicAdd(&cnt[epack[e] >> 17], 1);
    __syncthreads();
    int v = 0;
    if (tid < NPB) {
        v = cnt[tid];
        ts[tid] = v;
    }
    __syncthreads();
    for (int off = 1; off < NPB; off <<= 1) {
        int t = (tid < NPB && tid >= off) ? ts[tid - off] : 0;
        __syncthreads();
        if (tid < NPB) ts[tid] += t;
        __syncthreads();
    }
    if (tid < NPB) {
        int loff = ts[tid] - v;
        int node = nbase + tid;
        if (node < NN) {
            row_beg[node] = ebase + loff;
            row_deg[node] = v;
            deg_inv[node] = rsqrtf(1.0f + (float)v);
        }
        cnt[tid] = loff;  // reuse as cursor
    }
    __syncthreads();
    for (int e = ebase + tid; e < eend; e += 512) {
        int rec = epack[e];
        int r = atomicAdd(&cnt[rec >> 17], 1);
        __builtin_nontemporal_store(rec & 0x1FFFF, &col[ebase + r]);
    }
}

// ---------------- GEMM1: [N,128]@[128,32], reg-tiled, bf16 split-half output ----------------
// x reads non-temporal as 4 scalar floats (HIP vector types rejected by the builtin);
// adjacent nt scalars coalesce. Writes hA (feats 0-15) / hB (16-31): 3.2 MB half tables.
__global__ __launch_bounds__(256) void gemm_x_w1(const float* __restrict__ x,
                                                 const float* __restrict__ W,
                                                 const float* __restrict__ deg_inv,
                                                 unsigned short* __restrict__ hA,
                                                 unsigned short* __restrict__ hB, int N) {
    __shared__ float wsh[128 * 32];      // 16 KB
    __shared__ float xs[32][132];        // pad 128->132: rows hit distinct banks
    int tid = threadIdx.x;
    int row0 = blockIdx.x * 32;
    if (blockIdx.x == 0 && tid < 8) {    // dummy zero row at index NN, both halves
        unsigned short* hp = (tid < 4) ? hA : hB;
        *(ushort4*)&hp[(size_t)NN * 16 + (tid & 3) * 4] = make_ushort4(0, 0, 0, 0);
    }
    for (int i = tid; i < 1024; i += 256)
        ((float4*)wsh)[i] = ((const float4*)W)[i];
    for (int i = tid; i < 1024; i += 256) {
        int r = i >> 5, c4 = i & 31;
        const float* xp = x + (size_t)(row0 + r) * 128 + c4 * 4;
        float v0 = __builtin_nontemporal_load(xp + 0);
        float v1 = __builtin_nontemporal_load(xp + 1);
        float v2 = __builtin_nontemporal_load(xp + 2);
        float v3 = __builtin_nontemporal_load(xp + 3);
        float* dp = &xs[r][c4 * 4];
        dp[0] = v0; dp[1] = v1; dp[2] = v2; dp[3] = v3;
    }
    __syncthreads();
    int r = tid >> 3;
    int c8 = (tid & 7) * 4;
    float acc0 = 0.f, acc1 = 0.f, acc2 = 0.f, acc3 = 0.f;
#pragma unroll
    for (int k0 = 0; k0 < 128; k0 += 4) {
        float4 xv = *(const float4*)&xs[r][k0];
#pragma unroll
        for (int j = 0; j < 4; ++j) {
            float xk = (&xv.x)[j];
            float4 wv = *(const float4*)&wsh[(k0 + j) * 32 + c8];
            acc0 += xk * wv.x;
            acc1 += xk * wv.y;
            acc2 += xk * wv.z;
            acc3 += xk * wv.w;
        }
    }
    float di = deg_inv[row0 + r];
    ushort4 o;
    o.x = f2bf(acc0 * di);
    o.y = f2bf(acc1 * di);
    o.z = f2bf(acc2 * di);
    o.w = f2bf(acc3 * di);
    unsigned short* hdst = (c8 < 16) ? hA : hB;
    *(ushort4*)&hdst[(size_t)(row0 + r) * 16 + (c8 & 15)] = o;
}

// ---------------- gather conv, 16-feat half (bf16), one node per 8 lanes ----------------
// Half table = 3.2 MB -> per-XCD L2 resident; col reads non-temporal so they don't
// evict it. Lane L owns feats 2L,2L+1 of the half via one uint. 8-deep unroll +
// col prefetch; invalid slots gather dummy zero row NN.
// MODE 0: t1half[node] = bf16( di^2*acc + di*b )   (feeds layer-2 conv of same half)
// MODE 1: fused mean-pooling into gsum[.][HALF*16..] ; gcnt only from HALF 0.
template <int MODE, int HALF>
__global__ __launch_bounds__(512) void conv_half(const int* __restrict__ row_beg,
                                                 const int* __restrict__ row_deg,
                                                 const int* __restrict__ col,
                                                 const unsigned int* __restrict__ h,
                                                 const float* __restrict__ deg_inv,
                                                 const float* __restrict__ bias,
                                                 unsigned int* __restrict__ outh,
                                                 const int* __restrict__ batch,
                                                 float* __restrict__ gsum,
                                                 float* __restrict__ gcnt) {
    __shared__ float sacc[2][16];
    __shared__ float scnt[2];
    __shared__ int sg[2];
    int tid = threadIdx.x;
    int gid = blockIdx.x * 512 + tid;
    int node = gid >> 3;
    int L = gid & 7;
    if (MODE == 0) {
        if (blockIdx.x == 0 && tid < 8)    // dummy zero row for layer-2 gathers
            outh[(size_t)NN * 8 + tid] = 0u;
    } else {
        if (tid < 32) sacc[tid >> 4][tid & 15] = 0.f;
        if (tid < 2) scnt[tid] = 0.f;
        if (tid == 0) {
            int nb = blockIdx.x * 64;
            sg[0] = batch[nb];
            sg[1] = batch[min(nb + 63, NN - 1)];
        }
    }
    bool valid = node < NN;
    float o0 = 0.f, o1 = 0.f;
    if (valid) {
        int beg = row_beg[node];
        int end = beg + row_deg[node];
        unsigned int sv = h[(size_t)node * 8 + L];  // self loop
        float2 s = bf2x2(sv);
        float a0x = s.x, a0y = s.y;
        float a1x = 0.f, a1y = 0.f, a2x = 0.f, a2y = 0.f, a3x = 0.f, a3y = 0.f;
        int myc = (beg + L < end) ? __builtin_nontemporal_load(&col[beg + L]) : NN;
        for (int j0 = beg; j0 < end; j0 += 8) {
            // prefetch next chunk's col (independent of gathers below)
            int nxt = (j0 + 8 + L < end) ? __builtin_nontemporal_load(&col[j0 + 8 + L]) : NN;
            int i0 = __shfl(myc, 0, 8) * 8 + L;
            int i1 = __shfl(myc, 1, 8) * 8 + L;
            int i2 = __shfl(myc, 2, 8) * 8 + L;
            int i3 = __shfl(myc, 3, 8) * 8 + L;
            int i4 = __shfl(myc, 4, 8) * 8 + L;
            int i5 = __shfl(myc, 5, 8) * 8 + L;
            int i6 = __shfl(myc, 6, 8) * 8 + L;
            int i7 = __shfl(myc, 7, 8) * 8 + L;
            unsigned int v0 = h[i0];
            unsigned int v1 = h[i1];
            unsigned int v2 = h[i2];
            unsigned int v3 = h[i3];
            unsigned int v4 = h[i4];
            unsigned int v5 = h[i5];
            unsigned int v6 = h[i6];
            unsigned int v7 = h[i7];
            float2 p;
            p = bf2x2(v0); a0x += p.x; a0y += p.y;
            p = bf2x2(v1); a1x += p.x; a1y += p.y;
            p = bf2x2(v2); a2x += p.x; a2y += p.y;
            p = bf2x2(v3); a3x += p.x; a3y += p.y;
            p = bf2x2(v4); a0x += p.x; a0y += p.y;
            p = bf2x2(v5); a1x += p.x; a1y += p.y;
            p = bf2x2(v6); a2x += p.x; a2y += p.y;
            p = bf2x2(v7); a3x += p.x; a3y += p.y;
            myc = nxt;
        }
        float c0 = (a0x + a1x) + (a2x + a3x);
        float c1 = (a0y + a1y) + (a2y + a3y);
        float di = deg_inv[node];
        if (MODE == 0) {
            o0 = di * di * c0 + di * bias[HALF * 16 + 2 * L];
            o1 = di * di * c1 + di * bias[HALF * 16 + 2 * L + 1];
            outh[(size_t)node * 8 + L] = bfpack(o0, o1);
        } else {
            o0 = di * c0;
            o1 = di * c1;
        }
    }
    if (MODE == 1) {
        __syncthreads();   // init (sacc/scnt/sg) visible before any LDS atomic
        if (valid) {
            int gn = batch[node];
            int fb = 2 * L;
            if (gn == sg[0]) {
                atomicAdd(&sacc[0][fb], o0);
                atomicAdd(&sacc[0][fb + 1], o1);
                if (HALF == 0 && L == 0) atomicAdd(&scnt[0], 1.f);
            } else if (gn == sg[1]) {
                atomicAdd(&sacc[1][fb], o0);
                atomicAdd(&sacc[1][fb + 1], o1);
                if (HALF == 0 && L == 0) atomicAdd(&scnt[1], 1.f);
            } else {  // >2 graphs in a 64-node window: ~13 sigma, kept for safety
                unsafeAtomicAdd(&gsum[gn * 32 + HALF * 16 + fb], o0);
                unsafeAtomicAdd(&gsum[gn * 32 + HALF * 16 + fb + 1], o1);
                if (HALF == 0 && L == 0) unsafeAtomicAdd(&gcnt[gn], 1.f);
            }
        }
        __syncthreads();
        if (tid < 32) {
            int s = tid >> 4, f = tid & 15;
            if (s == 0 || sg[1] != sg[0])
                unsafeAtomicAdd(&gsum[sg[s] * 32 + HALF * 16 + f], sacc[s][f]);
        }
        if (HALF == 0) {
            if (tid == 0) unsafeAtomicAdd(&gcnt[sg[0]], scnt[0]);
            if (tid == 1 && sg[1] != sg[0]) unsafeAtomicAdd(&gcnt[sg[1]], scnt[1]);
        }
    }
}

// ---------------- head: Wc fold + z=relu(p32@Wc+bc) -> BN -> fc2 -> softplus ----------------
// 1024 threads: fold is one (k,ch) pair per thread; z-compute is 4 threads/graph.
__global__ __launch_bounds__(1024) void head_kernel(const float* __restrict__ gsum,
                                                    const float* __restrict__ gcnt,
                                                    const float* __restrict__ W2,
                                                    const float* __restrict__ b2,
                                                    const float* __restrict__ fcW1,
                                                    const float* __restrict__ fcb1,
                                                    const float* __restrict__ gamma,
                                                    const float* __restrict__ beta,
                                                    const float* __restrict__ fcW2,
                                                    const float* __restrict__ fcb2,
                                                    float* __restrict__ out) {
    __shared__ float zs[NG][33];
    __shared__ float wcs[32 * 32];
    __shared__ float bcs[32];
    __shared__ float part1[32][32];
    __shared__ float part2[32][32];
    __shared__ float mu[32], rstd[32];
    int g = threadIdx.x;

    {   // fold Wc = W2@fcW1 into LDS: one (k,ch) per thread, float4 W2 reads
        int k = g >> 5, ch = g & 31;
        const float4* w2r = (const float4*)(W2 + k * 64);
        float a = 0.f;
#pragma unroll
        for (int j4 = 0; j4 < 16; ++j4) {
            float4 w = w2r[j4];
            a += w.x * fcW1[(j4 * 4 + 0) * 32 + ch];
            a += w.y * fcW1[(j4 * 4 + 1) * 32 + ch];
            a += w.z * fcW1[(j4 * 4 + 2) * 32 + ch];
            a += w.w * fcW1[(j4 * 4 + 3) * 32 + ch];
        }
        wcs[g] = a;
    }
    if (g < 32) {
        float a = fcb1[g];
#pragma unroll
        for (int j = 0; j < 64; ++j) a += b2[j] * fcW1[j * 32 + g];
        bcs[g] = a;
    }
    __syncthreads();

    {   // z = relu(p32 @ Wc + bc): 4 threads per graph, 8 channels each
        int gr = g >> 2, sub = g & 3;
        float inv = 1.0f / fmaxf(gcnt[gr], 1.0f);
        float p32[32];
        const float4* gs4 = (const float4*)(gsum + gr * 32);
#pragma unroll
        for (int q = 0; q < 8; ++q) {
            float4 v = gs4[q];
            p32[q * 4 + 0] = v.x * inv;
            p32[q * 4 + 1] = v.y * inv;
            p32[q * 4 + 2] = v.z * inv;
            p32[q * 4 + 3] = v.w * inv;
        }
#pragma unroll
        for (int cc = 0; cc < 8; ++cc) {
            int ch = sub * 8 + cc;
            float acc = bcs[ch];
#pragma unroll
            for (int k = 0; k < 32; ++k) acc += p32[k] * wcs[k * 32 + ch];
            zs[gr][ch] = fmaxf(acc, 0.f);
        }
    }
    __syncthreads();

    {   // BN stats: 32 segs x 32 ch, 8 rows per seg
        int ch = g & 31, seg = g >> 5;
        float s = 0.f, sq = 0.f;
#pragma unroll
        for (int i = 0; i < 8; ++i) {
            float v = zs[seg * 8 + i][ch];
            s += v;
            sq += v * v;
        }
        part1[seg][ch] = s;
        part2[seg][ch] = sq;
    }
    __syncthreads();
    if (g < 32) {
        float s = 0.f, sq = 0.f;
#pragma unroll
        for (int i = 0; i < 32; ++i) { s += part1[i][g]; sq += part2[i][g]; }
        float m = s / NG;
        float v = sq / NG - m * m;
        mu[g] = m;
        rstd[g] = rsqrtf(fmaxf(v, 0.f) + 1e-5f);
    }
    __syncthreads();

    if (g < NG) {
        float acc = fcb2[0];
#pragma unroll 4
        for (int ch = 0; ch < 32; ++ch) {
            float zn = (zs[g][ch] - mu[ch]) * rstd[ch] * gamma[ch] + beta[ch];
            acc += zn * fcW2[ch];
        }
        out[g] = fmaxf(acc, 0.f) + log1pf(expf(-fabsf(acc)));
    }
}

extern "C" void kernel_launch(void* const* d_in, const int* in_sizes, int n_in,
                              void* d_out, int out_size, void* d_ws, size_t ws_size,
                              hipStream_t stream) {
    const float* x     = (const float*)d_in[0];
    const int*   ei    = (const int*)d_in[1];
    const int*   batch = (const int*)d_in[2];
    const float* W1    = (const float*)d_in[3];
    const float* b1    = (const float*)d_in[4];
    const float* W2    = (const float*)d_in[5];
    const float* b2    = (const float*)d_in[6];
    const float* fcW1  = (const float*)d_in[7];
    const float* fcb1  = (const float*)d_in[8];
    const float* gamma = (const float*)d_in[9];
    const float* beta  = (const float*)d_in[10];
    const float* fcW2  = (const float*)d_in[11];
    const float* fcb2  = (const float*)d_in[12];
    float* out = (float*)d_out;

    // workspace layout (16B aligned; bkt_cur|gsum|gcnt contiguous -> ONE memset)
    char* p = (char*)d_ws;
    int*   bkt_cur = (int*)p;        p += 400 * 4;
    float* gsum    = (float*)p;      p += (size_t)NG * 32 * 4;
    float* gcnt    = (float*)p;      p += (size_t)NG * 4;
    float* deg_inv = (float*)p;      p += (size_t)NN * 4;
    int*   row_beg = (int*)p;        p += (size_t)(NN + 8) * 4;
    int*   row_deg = (int*)p;        p += (size_t)(NN + 8) * 4;
    int*   epack   = (int*)p;        p += (size_t)NBKT * STRIDE * 4;
    int*   col     = (int*)p;        p += (size_t)NBKT * STRIDE * 4;
    unsigned short* hA  = (unsigned short*)p;  p += (size_t)(NN + 1) * 16 * 2;  // bf16 half, +dummy
    unsigned short* hB  = (unsigned short*)p;  p += (size_t)(NN + 1) * 16 * 2;
    unsigned int*   t1A = (unsigned int*)p;    p += (size_t)(NN + 1) * 8 * 4;   // bf16x2/lane, +dummy
    unsigned int*   t1B = (unsigned int*)p;    p += (size_t)(NN + 1) * 8 * 4;

    const int* srcv = ei;
    const int* dstv = ei + NE;

    (void)hipMemsetAsync(bkt_cur, 0, 400 * 4 + (size_t)NG * 32 * 4 + (size_t)NG * 4, stream);

    // CSR build: partition into fixed-stride regions -> per-bucket build
    part_kernel<<<NB_P1, 1024, 0, stream>>>(srcv, dstv, bkt_cur, epack);
    build_kernel<<<NBKT, 512, 0, stream>>>(epack, bkt_cur, row_beg, row_deg, col, deg_inv);

    // layer 1 GEMM: h(A|B) = (x@W1)*deg_inv, split into 16-feat halves (3.2 MB each)
    gemm_x_w1<<<NN / 32, 256, 0, stream>>>(x, W1, deg_inv, hA, hB, NN);

    // half A: conv1 -> t1A, then layer-2 aggregation + pooling (t1A still L2-warm)
    conv_half<0, 0><<<NB_CONV, 512, 0, stream>>>(row_beg, row_deg, col, (const unsigned int*)hA,
                                                 deg_inv, b1, t1A, nullptr, nullptr, nullptr);
    conv_half<1, 0><<<NB_CONV, 512, 0, stream>>>(row_beg, row_deg, col, (const unsigned int*)t1A,
                                                 deg_inv, nullptr, nullptr, batch, gsum, gcnt);
    // half B
    conv_half<0, 1><<<NB_CONV, 512, 0, stream>>>(row_beg, row_deg, col, (const unsigned int*)hB,
                                                 deg_inv, b1, t1B, nullptr, nullptr, nullptr);
    conv_half<1, 1><<<NB_CONV, 512, 0, stream>>>(row_beg, row_deg, col, (const unsigned int*)t1B,
                                                 deg_inv, nullptr, nullptr, batch, gsum, gcnt);

    // head
    head_kernel<<<1, 1024, 0, stream>>>(gsum, gcnt, W2, b2, fcW1, fcb1, gamma, beta, fcW2, fcb2, out);
}

// Round 9
// 226.943 us; speedup vs baseline: 1.1670x; 1.1670x over previous
//
#include <hip/hip_runtime.h>

#define NN 100000
#define NE 1600000
#define NG 256

#define BSH 8                 // bucket = dst >> 8  (256 nodes/bucket)
#define NPB 256               // nodes per bucket
#define NBKT ((NN + NPB - 1) / NPB)   // 391
#define STRIDE 4608           // fixed bucket region (mean 4096, +8 sigma)
#define TILE 8192
#define NB_P1 ((NE + TILE - 1) / TILE) // 196

__device__ __forceinline__ unsigned short f2bf(float x) {
    unsigned int u = __float_as_uint(x);
    u += 0x7FFFu + ((u >> 16) & 1u);   // round-to-nearest-even
    return (unsigned short)(u >> 16);
}
__device__ __forceinline__ float2 bf2x2(unsigned int v) {
    float2 r;
    r.x = __uint_as_float(v << 16);
    r.y = __uint_as_float(v & 0xFFFF0000u);
    return r;
}
__device__ __forceinline__ unsigned int bfpack(float x, float y) {
    return (unsigned int)f2bf(x) | ((unsigned int)f2bf(y) << 16);
}

// ---- partition edges into fixed-stride bucket regions (packed: src | local<<17) ----
// Multisplit: reorder tile in LDS so global writes are dense & coalesced.
__global__ __launch_bounds__(1024) void part_kernel(const int* __restrict__ src,
                                                    const int* __restrict__ dst,
                                                    int* __restrict__ bkt_cur,
                                                    int* __restrict__ epack) {
    __shared__ int hist[512];                 // padded to 512 for scan (NBKT=391)
    __shared__ int scan0[512];
    __shared__ int cur[NBKT];                 // LDS write cursors
    __shared__ int gbase[NBKT];               // global_base - lds_exclusive_offset
    __shared__ int stage[TILE];               // 32 KB staged packed edges
    __shared__ unsigned short sb[TILE];       // 16 KB bucket id per staged slot
    int tid = threadIdx.x;
    int e0 = blockIdx.x * TILE;
    int e1 = min(e0 + TILE, NE);
    int n = e1 - e0;

    for (int i = tid; i < 512; i += 1024) hist[i] = 0;
    __syncthreads();

    // read edges once into registers (nt loads: pure stream, keep L2 clean)
    int d_[8], s_[8];
#pragma unroll
    for (int k = 0; k < 8; ++k) {
        int e = e0 + tid + k * 1024;
        if (e < e1) {
            d_[k] = __builtin_nontemporal_load(&dst[e]);
            s_[k] = __builtin_nontemporal_load(&src[e]);
            atomicAdd(&hist[d_[k] >> BSH], 1);
        }
    }
    __syncthreads();

    // inclusive Hillis-Steele scan over 512 slots
    if (tid < 512) scan0[tid] = hist[tid];
    __syncthreads();
    for (int off = 1; off < 512; off <<= 1) {
        int t = (tid < 512 && tid >= off) ? scan0[tid - off] : 0;
        __syncthreads();
        if (tid < 512) scan0[tid] += t;
        __syncthreads();
    }
    if (tid < NBKT) {
        int h = hist[tid];
        int ex = scan0[tid] - h;               // exclusive offset in LDS
        cur[tid] = ex;
        gbase[tid] = tid * STRIDE + (h ? atomicAdd(&bkt_cur[tid], h) : 0) - ex;
    }
    __syncthreads();

    // scatter into LDS (cheap), record bucket id
#pragma unroll
    for (int k = 0; k < 8; ++k) {
        int e = e0 + tid + k * 1024;
        if (e < e1) {
            int d = d_[k];
            int bk = d >> BSH;
            int p = atomicAdd(&cur[bk], 1);
            stage[p] = s_[k] | ((d & (NPB - 1)) << 17);
            sb[p] = (unsigned short)bk;
        }
    }
    __syncthreads();

    // dense coalesced flush: per-bucket runs are contiguous in both LDS and global
    for (int j = tid; j < n; j += 1024) {
        int bk = sb[j];
        int a = gbase[bk] + j;
        if (a < (bk + 1) * STRIDE)             // overflow guard (8-sigma; never expected)
            epack[a] = stage[j];
    }
}

// ---- per-bucket fine CSR build (LDS only): row_beg/row_deg + deg_inv + col ----
// col store is a PLAIN store: scattered 4B nt stores caused 105 MB of partial-line
// HBM writes (round-8 counters). L2 write-combining handles this pattern fine.
__global__ __launch_bounds__(512) void build_kernel(const int* __restrict__ epack,
                                                    const int* __restrict__ bkt_cur,
                                                    int* __restrict__ row_beg,
                                                    int* __restrict__ row_deg,
                                                    int* __restrict__ col,
                                                    float* __restrict__ deg_inv) {
    __shared__ int cnt[NPB];
    __shared__ int ts[NPB];
    int b = blockIdx.x;
    int tid = threadIdx.x;
    int ebase = b * STRIDE;
    int eend = ebase + min(bkt_cur[b], STRIDE);
    int nbase = b << BSH;
    if (tid < NPB) cnt[tid] = 0;
    __syncthreads();
    for (int e = ebase + tid; e < eend; e += 512)
        atomicAdd(&cnt[epack[e] >> 17], 1);
    __syncthreads();
    int v = 0;
    if (tid < NPB) {
        v = cnt[tid];
        ts[tid] = v;
    }
    __syncthreads();
    for (int off = 1; off < NPB; off <<= 1) {
        int t = (tid < NPB && tid >= off) ? ts[tid - off] : 0;
        __syncthreads();
        if (tid < NPB) ts[tid] += t;
        __syncthreads();
    }
    if (tid < NPB) {
        int loff = ts[tid] - v;
        int node = nbase + tid;
        if (node < NN) {
            row_beg[node] = ebase + loff;
            row_deg[node] = v;
            deg_inv[node] = rsqrtf(1.0f + (float)v);
        }
        cnt[tid] = loff;  // reuse as cursor
    }
    __syncthreads();
    for (int e = ebase + tid; e < eend; e += 512) {
        int rec = epack[e];
        int r = atomicAdd(&cnt[rec >> 17], 1);
        col[ebase + r] = rec & 0x1FFFF;
    }
}

// ---------------- GEMM1: [N,128]@[128,32], reg-tiled, bf16 output ----------------
// x read non-temporal as 4 scalar floats (51 MB pure stream; protects L2).
// Also zero-fills the dummy row NN (gather target for padded edge slots).
__global__ __launch_bounds__(256) void gemm_x_w1(const float* __restrict__ x,
                                                 const float* __restrict__ W,
                                                 const float* __restrict__ deg_inv,
                                                 unsigned short* __restrict__ h, int N) {
    __shared__ float wsh[128 * 32];      // 16 KB
    __shared__ float xs[32][132];        // pad 128->132: rows hit distinct banks
    int tid = threadIdx.x;
    int row0 = blockIdx.x * 32;
    if (blockIdx.x == 0 && tid < 8)      // dummy zero row at index NN
        *(ushort4*)&h[(size_t)NN * 32 + tid * 4] = make_ushort4(0, 0, 0, 0);
    for (int i = tid; i < 1024; i += 256)
        ((float4*)wsh)[i] = ((const float4*)W)[i];
    for (int i = tid; i < 1024; i += 256) {
        int r = i >> 5, c4 = i & 31;
        const float* xp = x + (size_t)(row0 + r) * 128 + c4 * 4;
        float v0 = __builtin_nontemporal_load(xp + 0);
        float v1 = __builtin_nontemporal_load(xp + 1);
        float v2 = __builtin_nontemporal_load(xp + 2);
        float v3 = __builtin_nontemporal_load(xp + 3);
        float* dp = &xs[r][c4 * 4];
        dp[0] = v0; dp[1] = v1; dp[2] = v2; dp[3] = v3;
    }
    __syncthreads();
    int r = tid >> 3;
    int c8 = (tid & 7) * 4;
    float acc0 = 0.f, acc1 = 0.f, acc2 = 0.f, acc3 = 0.f;
#pragma unroll
    for (int k0 = 0; k0 < 128; k0 += 4) {
        float4 xv = *(const float4*)&xs[r][k0];
#pragma unroll
        for (int j = 0; j < 4; ++j) {
            float xk = (&xv.x)[j];
            float4 wv = *(const float4*)&wsh[(k0 + j) * 32 + c8];
            acc0 += xk * wv.x;
            acc1 += xk * wv.y;
            acc2 += xk * wv.z;
            acc3 += xk * wv.w;
        }
    }
    float di = deg_inv[row0 + r];
    ushort4 o;
    o.x = f2bf(acc0 * di);
    o.y = f2bf(acc1 * di);
    o.z = f2bf(acc2 * di);
    o.w = f2bf(acc3 * di);
    *(ushort4*)&h[(size_t)(row0 + r) * 32 + c8] = o;
}

// ---------------- gather conv F=32 (bf16), one node per 8 lanes ----------------
// Lane L owns feats 4L..4L+3 via uint2. 8-deep unroll + nt col prefetch: 9
// outstanding VMEM/wave. Invalid edge slots gather dummy zero row NN (no masking).
// MODE 0: t1[node] = bf16( di^2*acc + di*b )   (feeds conv2); writes t1 dummy row.
// MODE 1: fused mean-pooling into gsum/gcnt (batch sorted, <=2 graphs per 64-node window)
template <int MODE>
__global__ __launch_bounds__(512) void conv_bf_kernel(const int* __restrict__ row_beg,
                                                      const int* __restrict__ row_deg,
                                                      const int* __restrict__ col,
                                                      const uint2* __restrict__ h2,
                                                      const float* __restrict__ deg_inv,
                                                      const float* __restrict__ b,
                                                      uint2* __restrict__ out_bf,
                                                      const int* __restrict__ batch,
                                                      float* __restrict__ gsum,
                                                      float* __restrict__ gcnt) {
    __shared__ float sacc[2][32];
    __shared__ float scnt[2];
    __shared__ int sg[2];
    int tid = threadIdx.x;
    int gid = blockIdx.x * 512 + tid;
    int node = gid >> 3;
    int L = gid & 7;
    if (MODE == 0) {
        if (blockIdx.x == 0 && tid < 8)    // dummy zero row for layer-2 gathers
            out_bf[(size_t)NN * 8 + tid] = make_uint2(0u, 0u);
    } else {
        if (tid < 64) sacc[tid >> 5][tid & 31] = 0.f;
        if (tid < 2) scnt[tid] = 0.f;
        if (tid == 0) {
            int nb = blockIdx.x * 64;
            sg[0] = batch[nb];
            sg[1] = batch[min(nb + 63, NN - 1)];
        }
    }
    bool valid = node < NN;
    float o0 = 0.f, o1 = 0.f, o2 = 0.f, o3 = 0.f;
    if (valid) {
        int beg = row_beg[node];
        int end = beg + row_deg[node];
        uint2 sv = h2[node * 8 + L];  // self loop
        float2 s0 = bf2x2(sv.x), s1 = bf2x2(sv.y);
        float a00 = s0.x, a01 = s0.y, a02 = s1.x, a03 = s1.y;
        float a10 = 0.f, a11 = 0.f, a12 = 0.f, a13 = 0.f;
        float a20 = 0.f, a21 = 0.f, a22 = 0.f, a23 = 0.f;
        float a30 = 0.f, a31 = 0.f, a32 = 0.f, a33 = 0.f;
        int myc = (beg + L < end) ? __builtin_nontemporal_load(&col[beg + L]) : NN;
        for (int j0 = beg; j0 < end; j0 += 8) {
            // prefetch next chunk's col (independent of gathers below)
            int nxt = (j0 + 8 + L < end) ? __builtin_nontemporal_load(&col[j0 + 8 + L]) : NN;
            int i0 = __shfl(myc, 0, 8) * 8 + L;
            int i1 = __shfl(myc, 1, 8) * 8 + L;
            int i2 = __shfl(myc, 2, 8) * 8 + L;
            int i3 = __shfl(myc, 3, 8) * 8 + L;
            int i4 = __shfl(myc, 4, 8) * 8 + L;
            int i5 = __shfl(myc, 5, 8) * 8 + L;
            int i6 = __shfl(myc, 6, 8) * 8 + L;
            int i7 = __shfl(myc, 7, 8) * 8 + L;
            uint2 v0 = h2[i0];
            uint2 v1 = h2[i1];
            uint2 v2 = h2[i2];
            uint2 v3 = h2[i3];
            uint2 v4 = h2[i4];
            uint2 v5 = h2[i5];
            uint2 v6 = h2[i6];
            uint2 v7 = h2[i7];
            float2 p, q;
            p = bf2x2(v0.x); q = bf2x2(v0.y);
            a00 += p.x; a01 += p.y; a02 += q.x; a03 += q.y;
            p = bf2x2(v1.x); q = bf2x2(v1.y);
            a10 += p.x; a11 += p.y; a12 += q.x; a13 += q.y;
            p = bf2x2(v2.x); q = bf2x2(v2.y);
            a20 += p.x; a21 += p.y; a22 += q.x; a23 += q.y;
            p = bf2x2(v3.x); q = bf2x2(v3.y);
            a30 += p.x; a31 += p.y; a32 += q.x; a33 += q.y;
            p = bf2x2(v4.x); q = bf2x2(v4.y);
            a00 += p.x; a01 += p.y; a02 += q.x; a03 += q.y;
            p = bf2x2(v5.x); q = bf2x2(v5.y);
            a10 += p.x; a11 += p.y; a12 += q.x; a13 += q.y;
            p = bf2x2(v6.x); q = bf2x2(v6.y);
            a20 += p.x; a21 += p.y; a22 += q.x; a23 += q.y;
            p = bf2x2(v7.x); q = bf2x2(v7.y);
            a30 += p.x; a31 += p.y; a32 += q.x; a33 += q.y;
            myc = nxt;
        }
        float c0 = (a00 + a10) + (a20 + a30);
        float c1 = (a01 + a11) + (a21 + a31);
        float c2 = (a02 + a12) + (a22 + a32);
        float c3 = (a03 + a13) + (a23 + a33);
        float di = deg_inv[node];
        if (MODE == 0) {
            o0 = di * di * c0 + di * b[4 * L + 0];
            o1 = di * di * c1 + di * b[4 * L + 1];
            o2 = di * di * c2 + di * b[4 * L + 2];
            o3 = di * di * c3 + di * b[4 * L + 3];
            out_bf[node * 8 + L] = make_uint2(bfpack(o0, o1), bfpack(o2, o3));
        } else {
            o0 = di * c0; o1 = di * c1; o2 = di * c2; o3 = di * c3;
        }
    }
    if (MODE == 1) {
        __syncthreads();   // init (sacc/scnt/sg) visible before any LDS atomic
        if (valid) {
            int gn = batch[node];
            int fb = 4 * L;
            if (gn == sg[0]) {
                atomicAdd(&sacc[0][fb + 0], o0);
                atomicAdd(&sacc[0][fb + 1], o1);
                atomicAdd(&sacc[0][fb + 2], o2);
                atomicAdd(&sacc[0][fb + 3], o3);
                if (L == 0) atomicAdd(&scnt[0], 1.f);
            } else if (gn == sg[1]) {
                atomicAdd(&sacc[1][fb + 0], o0);
                atomicAdd(&sacc[1][fb + 1], o1);
                atomicAdd(&sacc[1][fb + 2], o2);
                atomicAdd(&sacc[1][fb + 3], o3);
                if (L == 0) atomicAdd(&scnt[1], 1.f);
            } else {  // >2 graphs in a 64-node window: ~13 sigma, kept for safety
                unsafeAtomicAdd(&gsum[gn * 32 + fb + 0], o0);
                unsafeAtomicAdd(&gsum[gn * 32 + fb + 1], o1);
                unsafeAtomicAdd(&gsum[gn * 32 + fb + 2], o2);
                unsafeAtomicAdd(&gsum[gn * 32 + fb + 3], o3);
                if (L == 0) unsafeAtomicAdd(&gcnt[gn], 1.f);
            }
        }
        __syncthreads();
        if (tid < 64) {
            int s = tid >> 5, f = tid & 31;
            if (s == 0 || sg[1] != sg[0])
                unsafeAtomicAdd(&gsum[sg[s] * 32 + f], sacc[s][f]);
        }
        if (tid == 0) unsafeAtomicAdd(&gcnt[sg[0]], scnt[0]);
        if (tid == 1 && sg[1] != sg[0]) unsafeAtomicAdd(&gcnt[sg[1]], scnt[1]);
    }
}

// ---------------- head: Wc fold + z=relu(p32@Wc+bc) -> BN -> fc2 -> softplus ----------------
// 1024 threads: fold is one (k,ch) pair per thread; z-compute is 4 threads/graph.
__global__ __launch_bounds__(1024) void head_kernel(const float* __restrict__ gsum,
                                                    const float* __restrict__ gcnt,
                                                    const float* __restrict__ W2,
                                                    const float* __restrict__ b2,
                                                    const float* __restrict__ fcW1,
                                                    const float* __restrict__ fcb1,
                                                    const float* __restrict__ gamma,
                                                    const float* __restrict__ beta,
                                                    const float* __restrict__ fcW2,
                                                    const float* __restrict__ fcb2,
                                                    float* __restrict__ out) {
    __shared__ float zs[NG][33];
    __shared__ float wcs[32 * 32];
    __shared__ float bcs[32];
    __shared__ float part1[32][32];
    __shared__ float part2[32][32];
    __shared__ float mu[32], rstd[32];
    int g = threadIdx.x;

    {   // fold Wc = W2@fcW1 into LDS: one (k,ch) per thread, float4 W2 reads
        int k = g >> 5, ch = g & 31;
        const float4* w2r = (const float4*)(W2 + k * 64);
        float a = 0.f;
#pragma unroll
        for (int j4 = 0; j4 < 16; ++j4) {
            float4 w = w2r[j4];
            a += w.x * fcW1[(j4 * 4 + 0) * 32 + ch];
            a += w.y * fcW1[(j4 * 4 + 1) * 32 + ch];
            a += w.z * fcW1[(j4 * 4 + 2) * 32 + ch];
            a += w.w * fcW1[(j4 * 4 + 3) * 32 + ch];
        }
        wcs[g] = a;
    }
    if (g < 32) {
        float a = fcb1[g];
#pragma unroll
        for (int j = 0; j < 64; ++j) a += b2[j] * fcW1[j * 32 + g];
        bcs[g] = a;
    }
    __syncthreads();

    {   // z = relu(p32 @ Wc + bc): 4 threads per graph, 8 channels each
        int gr = g >> 2, sub = g & 3;
        float inv = 1.0f / fmaxf(gcnt[gr], 1.0f);
        float p32[32];
        const float4* gs4 = (const float4*)(gsum + gr * 32);
#pragma unroll
        for (int q = 0; q < 8; ++q) {
            float4 v = gs4[q];
            p32[q * 4 + 0] = v.x * inv;
            p32[q * 4 + 1] = v.y * inv;
            p32[q * 4 + 2] = v.z * inv;
            p32[q * 4 + 3] = v.w * inv;
        }
#pragma unroll
        for (int cc = 0; cc < 8; ++cc) {
            int ch = sub * 8 + cc;
            float acc = bcs[ch];
#pragma unroll
            for (int k = 0; k < 32; ++k) acc += p32[k] * wcs[k * 32 + ch];
            zs[gr][ch] = fmaxf(acc, 0.f);
        }
    }
    __syncthreads();

    {   // BN stats: 32 segs x 32 ch, 8 rows per seg
        int ch = g & 31, seg = g >> 5;
        float s = 0.f, sq = 0.f;
#pragma unroll
        for (int i = 0; i < 8; ++i) {
            float v = zs[seg * 8 + i][ch];
            s += v;
            sq += v * v;
        }
        part1[seg][ch] = s;
        part2[seg][ch] = sq;
    }
    __syncthreads();
    if (g < 32) {
        float s = 0.f, sq = 0.f;
#pragma unroll
        for (int i = 0; i < 32; ++i) { s += part1[i][g]; sq += part2[i][g]; }
        float m = s / NG;
        float v = sq / NG - m * m;
        mu[g] = m;
        rstd[g] = rsqrtf(fmaxf(v, 0.f) + 1e-5f);
    }
    __syncthreads();

    if (g < NG) {
        float acc = fcb2[0];
#pragma unroll 4
        for (int ch = 0; ch < 32; ++ch) {
            float zn = (zs[g][ch] - mu[ch]) * rstd[ch] * gamma[ch] + beta[ch];
            acc += zn * fcW2[ch];
        }
        out[g] = fmaxf(acc, 0.f) + log1pf(expf(-fabsf(acc)));
    }
}

extern "C" void kernel_launch(void* const* d_in, const int* in_sizes, int n_in,
                              void* d_out, int out_size, void* d_ws, size_t ws_size,
                              hipStream_t stream) {
    const float* x     = (const float*)d_in[0];
    const int*   ei    = (const int*)d_in[1];
    const int*   batch = (const int*)d_in[2];
    const float* W1    = (const float*)d_in[3];
    const float* b1    = (const float*)d_in[4];
    const float* W2    = (const float*)d_in[5];
    const float* b2    = (const float*)d_in[6];
    const float* fcW1  = (const float*)d_in[7];
    const float* fcb1  = (const float*)d_in[8];
    const float* gamma = (const float*)d_in[9];
    const float* beta  = (const float*)d_in[10];
    const float* fcW2  = (const float*)d_in[11];
    const float* fcb2  = (const float*)d_in[12];
    float* out = (float*)d_out;

    // workspace layout (16B aligned; bkt_cur|gsum|gcnt contiguous -> ONE memset)
    char* p = (char*)d_ws;
    int*   bkt_cur = (int*)p;        p += 400 * 4;
    float* gsum    = (float*)p;      p += (size_t)NG * 32 * 4;
    float* gcnt    = (float*)p;      p += (size_t)NG * 4;
    float* deg_inv = (float*)p;      p += (size_t)NN * 4;
    int*   row_beg = (int*)p;        p += (size_t)(NN + 8) * 4;
    int*   row_deg = (int*)p;        p += (size_t)(NN + 8) * 4;
    int*   epack   = (int*)p;        p += (size_t)NBKT * STRIDE * 4;
    int*   col     = (int*)p;        p += (size_t)NBKT * STRIDE * 4;
    unsigned short* h1s = (unsigned short*)p;  p += (size_t)(NN + 1) * 32 * 2;  // bf16 (+dummy row)
    uint2*          t1  = (uint2*)p;           p += (size_t)(NN + 1) * 8 * 8;   // bf16x4/lane (+dummy row)

    const int* srcv = ei;
    const int* dstv = ei + NE;

    (void)hipMemsetAsync(bkt_cur, 0, 400 * 4 + (size_t)NG * 32 * 4 + (size_t)NG * 4, stream);

    // CSR build: partition into fixed-stride regions -> per-bucket build
    part_kernel<<<NB_P1, 1024, 0, stream>>>(srcv, dstv, bkt_cur, epack);
    build_kernel<<<NBKT, 512, 0, stream>>>(epack, bkt_cur, row_beg, row_deg, col, deg_inv);

    // layer 1: h1s(bf16) = (x@W1)*deg_inv ; conv1 -> t1(bf16)
    gemm_x_w1<<<NN / 32, 256, 0, stream>>>(x, W1, deg_inv, h1s, NN);
    conv_bf_kernel<0><<<((size_t)NN * 8 + 511) / 512, 512, 0, stream>>>(
        row_beg, row_deg, col, (const uint2*)h1s, deg_inv, b1, t1, nullptr, nullptr, nullptr);

    // layer 2 aggregation (W2 folded into head) + fused mean-pooling
    conv_bf_kernel<1><<<((size_t)NN * 8 + 511) / 512, 512, 0, stream>>>(
        row_beg, row_deg, col, (const uint2*)t1, deg_inv, b1, nullptr, batch, gsum, gcnt);

    // head
    head_kernel<<<1, 1024, 0, stream>>>(gsum, gcnt, W2, b2, fcW1, fcb1, gamma, beta, fcW2, fcb2, out);
}

// Round 10
// 218.557 us; speedup vs baseline: 1.2118x; 1.0384x over previous
//
#include <hip/hip_runtime.h>

#define NN 100000
#define NE 1600000
#define NG 256

#define BSH 8                 // bucket = dst >> 8  (256 nodes/bucket)
#define NPB 256               // nodes per bucket
#define NBKT ((NN + NPB - 1) / NPB)   // 391
#define STRIDE 4608           // fixed bucket region (mean 4096, +8 sigma)
#define TILE 8192
#define NB_P1 ((NE + TILE - 1) / TILE) // 196

__device__ __forceinline__ unsigned short f2bf(float x) {
    unsigned int u = __float_as_uint(x);
    u += 0x7FFFu + ((u >> 16) & 1u);   // round-to-nearest-even
    return (unsigned short)(u >> 16);
}
__device__ __forceinline__ float2 bf2x2(unsigned int v) {
    float2 r;
    r.x = __uint_as_float(v << 16);
    r.y = __uint_as_float(v & 0xFFFF0000u);
    return r;
}
__device__ __forceinline__ unsigned int bfpack(float x, float y) {
    return (unsigned int)f2bf(x) | ((unsigned int)f2bf(y) << 16);
}

// ---- partition edges into fixed-stride bucket regions (packed: src | local<<17) ----
// Multisplit: reorder tile in LDS so global writes are dense & coalesced.
__global__ __launch_bounds__(1024) void part_kernel(const int* __restrict__ src,
                                                    const int* __restrict__ dst,
                                                    int* __restrict__ bkt_cur,
                                                    int* __restrict__ epack) {
    __shared__ int hist[512];                 // padded to 512 for scan (NBKT=391)
    __shared__ int scan0[512];
    __shared__ int cur[NBKT];                 // LDS write cursors
    __shared__ int gbase[NBKT];               // global_base - lds_exclusive_offset
    __shared__ int stage[TILE];               // 32 KB staged packed edges
    __shared__ unsigned short sb[TILE];       // 16 KB bucket id per staged slot
    int tid = threadIdx.x;
    int e0 = blockIdx.x * TILE;
    int e1 = min(e0 + TILE, NE);
    int n = e1 - e0;

    for (int i = tid; i < 512; i += 1024) hist[i] = 0;
    __syncthreads();

    // read edges once into registers, histogram dst buckets
    int d_[8], s_[8];
#pragma unroll
    for (int k = 0; k < 8; ++k) {
        int e = e0 + tid + k * 1024;
        if (e < e1) {
            d_[k] = dst[e];
            s_[k] = src[e];
            atomicAdd(&hist[d_[k] >> BSH], 1);
        }
    }
    __syncthreads();

    // inclusive Hillis-Steele scan over 512 slots
    if (tid < 512) scan0[tid] = hist[tid];
    __syncthreads();
    for (int off = 1; off < 512; off <<= 1) {
        int t = (tid < 512 && tid >= off) ? scan0[tid - off] : 0;
        __syncthreads();
        if (tid < 512) scan0[tid] += t;
        __syncthreads();
    }
    if (tid < NBKT) {
        int h = hist[tid];
        int ex = scan0[tid] - h;               // exclusive offset in LDS
        cur[tid] = ex;
        gbase[tid] = tid * STRIDE + (h ? atomicAdd(&bkt_cur[tid], h) : 0) - ex;
    }
    __syncthreads();

    // scatter into LDS (cheap), record bucket id
#pragma unroll
    for (int k = 0; k < 8; ++k) {
        int e = e0 + tid + k * 1024;
        if (e < e1) {
            int d = d_[k];
            int bk = d >> BSH;
            int p = atomicAdd(&cur[bk], 1);
            stage[p] = s_[k] | ((d & (NPB - 1)) << 17);
            sb[p] = (unsigned short)bk;
        }
    }
    __syncthreads();

    // dense coalesced flush: per-bucket runs are contiguous in both LDS and global
    for (int j = tid; j < n; j += 1024) {
        int bk = sb[j];
        int a = gbase[bk] + j;
        if (a < (bk + 1) * STRIDE)             // overflow guard (8-sigma; never expected)
            epack[a] = stage[j];
    }
}

// ---- per-bucket fine CSR build (LDS only): row_beg/row_deg + deg_inv + col ----
__global__ __launch_bounds__(512) void build_kernel(const int* __restrict__ epack,
                                                    const int* __restrict__ bkt_cur,
                                                    int* __restrict__ row_beg,
                                                    int* __restrict__ row_deg,
                                                    int* __restrict__ col,
                                                    float* __restrict__ deg_inv) {
    __shared__ int cnt[NPB];
    __shared__ int ts[NPB];
    int b = blockIdx.x;
    int tid = threadIdx.x;
    int ebase = b * STRIDE;
    int eend = ebase + min(bkt_cur[b], STRIDE);
    int nbase = b << BSH;
    if (tid < NPB) cnt[tid] = 0;
    __syncthreads();
    for (int e = ebase + tid; e < eend; e += 512)
        atomicAdd(&cnt[epack[e] >> 17], 1);
    __syncthreads();
    int v = 0;
    if (tid < NPB) {
        v = cnt[tid];
        ts[tid] = v;
    }
    __syncthreads();
    for (int off = 1; off < NPB; off <<= 1) {
        int t = (tid < NPB && tid >= off) ? ts[tid - off] : 0;
        __syncthreads();
        if (tid < NPB) ts[tid] += t;
        __syncthreads();
    }
    if (tid < NPB) {
        int loff = ts[tid] - v;
        int node = nbase + tid;
        if (node < NN) {
            row_beg[node] = ebase + loff;
            row_deg[node] = v;
            deg_inv[node] = rsqrtf(1.0f + (float)v);
        }
        cnt[tid] = loff;  // reuse as cursor
    }
    __syncthreads();
    for (int e = ebase + tid; e < eend; e += 512) {
        int rec = epack[e];
        int r = atomicAdd(&cnt[rec >> 17], 1);
        col[ebase + r] = rec & 0x1FFFF;
    }
}

// ---------------- GEMM1: [N,128]@[128,32], reg-tiled, bf16 output ----------------
// Also zero-fills the dummy row NN (gather target for padded edge slots).
__global__ __launch_bounds__(256) void gemm_x_w1(const float* __restrict__ x,
                                                 const float* __restrict__ W,
                                                 const float* __restrict__ deg_inv,
                                                 unsigned short* __restrict__ h, int N) {
    __shared__ float wsh[128 * 32];      // 16 KB
    __shared__ float xs[32][132];        // pad 128->132: rows hit distinct banks
    int tid = threadIdx.x;
    int row0 = blockIdx.x * 32;
    if (blockIdx.x == 0 && tid < 8)      // dummy zero row at index NN
        *(ushort4*)&h[(size_t)NN * 32 + tid * 4] = make_ushort4(0, 0, 0, 0);
    for (int i = tid; i < 1024; i += 256)
        ((float4*)wsh)[i] = ((const float4*)W)[i];
    for (int i = tid; i < 1024; i += 256) {
        int r = i >> 5, c4 = i & 31;
        *(float4*)&xs[r][c4 * 4] = ((const float4*)(x + (size_t)(row0 + r) * 128))[c4];
    }
    __syncthreads();
    int r = tid >> 3;
    int c8 = (tid & 7) * 4;
    float acc0 = 0.f, acc1 = 0.f, acc2 = 0.f, acc3 = 0.f;
#pragma unroll
    for (int k0 = 0; k0 < 128; k0 += 4) {
        float4 xv = *(const float4*)&xs[r][k0];
#pragma unroll
        for (int j = 0; j < 4; ++j) {
            float xk = (&xv.x)[j];
            float4 wv = *(const float4*)&wsh[(k0 + j) * 32 + c8];
            acc0 += xk * wv.x;
            acc1 += xk * wv.y;
            acc2 += xk * wv.z;
            acc3 += xk * wv.w;
        }
    }
    float di = deg_inv[row0 + r];
    ushort4 o;
    o.x = f2bf(acc0 * di);
    o.y = f2bf(acc1 * di);
    o.z = f2bf(acc2 * di);
    o.w = f2bf(acc3 * di);
    *(ushort4*)&h[(size_t)(row0 + r) * 32 + c8] = o;
}

// ---------------- gather conv F=32 (bf16), one node per 8 lanes ----------------
// Lane L owns feats 4L..4L+3 via uint2. 8-deep unroll + col prefetch: 9
// outstanding VMEM/wave. Invalid edge slots gather dummy zero row NN (no masking).
// MODE 0: t1[node] = bf16( di^2*acc + di*b )   (feeds conv2); writes t1 dummy row.
// MODE 1: fused mean-pooling into gsum/gcnt (batch sorted, <=2 graphs per 64-node window)
template <int MODE>
__global__ __launch_bounds__(512) void conv_bf_kernel(const int* __restrict__ row_beg,
                                                      const int* __restrict__ row_deg,
                                                      const int* __restrict__ col,
                                                      const uint2* __restrict__ h2,
                                                      const float* __restrict__ deg_inv,
                                                      const float* __restrict__ b,
                                                      uint2* __restrict__ out_bf,
                                                      const int* __restrict__ batch,
                                                      float* __restrict__ gsum,
                                                      float* __restrict__ gcnt) {
    __shared__ float sacc[2][32];
    __shared__ float scnt[2];
    __shared__ int sg[2];
    int tid = threadIdx.x;
    int gid = blockIdx.x * 512 + tid;
    int node = gid >> 3;
    int L = gid & 7;
    if (MODE == 0) {
        if (blockIdx.x == 0 && tid < 8)    // dummy zero row for layer-2 gathers
            out_bf[(size_t)NN * 8 + tid] = make_uint2(0u, 0u);
    } else {
        if (tid < 64) sacc[tid >> 5][tid & 31] = 0.f;
        if (tid < 2) scnt[tid] = 0.f;
        if (tid == 0) {
            int nb = blockIdx.x * 64;
            sg[0] = batch[nb];
            sg[1] = batch[min(nb + 63, NN - 1)];
        }
    }
    bool valid = node < NN;
    float o0 = 0.f, o1 = 0.f, o2 = 0.f, o3 = 0.f;
    if (valid) {
        int beg = row_beg[node];
        int end = beg + row_deg[node];
        uint2 sv = h2[node * 8 + L];  // self loop
        float2 s0 = bf2x2(sv.x), s1 = bf2x2(sv.y);
        float a00 = s0.x, a01 = s0.y, a02 = s1.x, a03 = s1.y;
        float a10 = 0.f, a11 = 0.f, a12 = 0.f, a13 = 0.f;
        float a20 = 0.f, a21 = 0.f, a22 = 0.f, a23 = 0.f;
        float a30 = 0.f, a31 = 0.f, a32 = 0.f, a33 = 0.f;
        int myc = (beg + L < end) ? col[beg + L] : NN;
        for (int j0 = beg; j0 < end; j0 += 8) {
            // prefetch next chunk's col (independent of gathers below)
            int nxt = (j0 + 8 + L < end) ? col[j0 + 8 + L] : NN;
            int i0 = __shfl(myc, 0, 8) * 8 + L;
            int i1 = __shfl(myc, 1, 8) * 8 + L;
            int i2 = __shfl(myc, 2, 8) * 8 + L;
            int i3 = __shfl(myc, 3, 8) * 8 + L;
            int i4 = __shfl(myc, 4, 8) * 8 + L;
            int i5 = __shfl(myc, 5, 8) * 8 + L;
            int i6 = __shfl(myc, 6, 8) * 8 + L;
            int i7 = __shfl(myc, 7, 8) * 8 + L;
            uint2 v0 = h2[i0];
            uint2 v1 = h2[i1];
            uint2 v2 = h2[i2];
            uint2 v3 = h2[i3];
            uint2 v4 = h2[i4];
            uint2 v5 = h2[i5];
            uint2 v6 = h2[i6];
            uint2 v7 = h2[i7];
            float2 p, q;
            p = bf2x2(v0.x); q = bf2x2(v0.y);
            a00 += p.x; a01 += p.y; a02 += q.x; a03 += q.y;
            p = bf2x2(v1.x); q = bf2x2(v1.y);
            a10 += p.x; a11 += p.y; a12 += q.x; a13 += q.y;
            p = bf2x2(v2.x); q = bf2x2(v2.y);
            a20 += p.x; a21 += p.y; a22 += q.x; a23 += q.y;
            p = bf2x2(v3.x); q = bf2x2(v3.y);
            a30 += p.x; a31 += p.y; a32 += q.x; a33 += q.y;
            p = bf2x2(v4.x); q = bf2x2(v4.y);
            a00 += p.x; a01 += p.y; a02 += q.x; a03 += q.y;
            p = bf2x2(v5.x); q = bf2x2(v5.y);
            a10 += p.x; a11 += p.y; a12 += q.x; a13 += q.y;
            p = bf2x2(v6.x); q = bf2x2(v6.y);
            a20 += p.x; a21 += p.y; a22 += q.x; a23 += q.y;
            p = bf2x2(v7.x); q = bf2x2(v7.y);
            a30 += p.x; a31 += p.y; a32 += q.x; a33 += q.y;
            myc = nxt;
        }
        float c0 = (a00 + a10) + (a20 + a30);
        float c1 = (a01 + a11) + (a21 + a31);
        float c2 = (a02 + a12) + (a22 + a32);
        float c3 = (a03 + a13) + (a23 + a33);
        float di = deg_inv[node];
        if (MODE == 0) {
            o0 = di * di * c0 + di * b[4 * L + 0];
            o1 = di * di * c1 + di * b[4 * L + 1];
            o2 = di * di * c2 + di * b[4 * L + 2];
            o3 = di * di * c3 + di * b[4 * L + 3];
            out_bf[node * 8 + L] = make_uint2(bfpack(o0, o1), bfpack(o2, o3));
        } else {
            o0 = di * c0; o1 = di * c1; o2 = di * c2; o3 = di * c3;
        }
    }
    if (MODE == 1) {
        __syncthreads();   // init (sacc/scnt/sg) visible before any LDS atomic
        if (valid) {
            int gn = batch[node];
            int fb = 4 * L;
            if (gn == sg[0]) {
                atomicAdd(&sacc[0][fb + 0], o0);
                atomicAdd(&sacc[0][fb + 1], o1);
                atomicAdd(&sacc[0][fb + 2], o2);
                atomicAdd(&sacc[0][fb + 3], o3);
                if (L == 0) atomicAdd(&scnt[0], 1.f);
            } else if (gn == sg[1]) {
                atomicAdd(&sacc[1][fb + 0], o0);
                atomicAdd(&sacc[1][fb + 1], o1);
                atomicAdd(&sacc[1][fb + 2], o2);
                atomicAdd(&sacc[1][fb + 3], o3);
                if (L == 0) atomicAdd(&scnt[1], 1.f);
            } else {  // >2 graphs in a 64-node window: ~13 sigma, kept for safety
                unsafeAtomicAdd(&gsum[gn * 32 + fb + 0], o0);
                unsafeAtomicAdd(&gsum[gn * 32 + fb + 1], o1);
                unsafeAtomicAdd(&gsum[gn * 32 + fb + 2], o2);
                unsafeAtomicAdd(&gsum[gn * 32 + fb + 3], o3);
                if (L == 0) unsafeAtomicAdd(&gcnt[gn], 1.f);
            }
        }
        __syncthreads();
        if (tid < 64) {
            int s = tid >> 5, f = tid & 31;
            if (s == 0 || sg[1] != sg[0])
                unsafeAtomicAdd(&gsum[sg[s] * 32 + f], sacc[s][f]);
        }
        if (tid == 0) unsafeAtomicAdd(&gcnt[sg[0]], scnt[0]);
        if (tid == 1 && sg[1] != sg[0]) unsafeAtomicAdd(&gcnt[sg[1]], scnt[1]);
    }
}

// ---------------- head: Wc fold + z=relu(p32@Wc+bc) -> BN -> fc2 -> softplus ----------------
__global__ __launch_bounds__(256) void head_kernel(const float* __restrict__ gsum,
                                                   const float* __restrict__ gcnt,
                                                   const float* __restrict__ W2,
                                                   const float* __restrict__ b2,
                                                   const float* __restrict__ fcW1,
                                                   const float* __restrict__ fcb1,
                                                   const float* __restrict__ gamma,
                                                   const float* __restrict__ beta,
                                                   const float* __restrict__ fcW2,
                                                   const float* __restrict__ fcb2,
                                                   float* __restrict__ out) {
    __shared__ float zs[NG][33];
    __shared__ float wcs[32 * 32];
    __shared__ float bcs[32];
    __shared__ float part1[8][32];
    __shared__ float part2[8][32];
    __shared__ float mu[32], rstd[32];
    int g = threadIdx.x;

    // fold Wc = W2@fcW1, bc = b2@fcW1+fcb1 directly into LDS
    for (int idx = g; idx < 32 * 32; idx += 256) {
        int k = idx / 32, ch = idx % 32;
        float a = 0.f;
#pragma unroll
        for (int j = 0; j < 64; ++j) a += W2[k * 64 + j] * fcW1[j * 32 + ch];
        wcs[idx] = a;
    }
    if (g < 32) {
        float a = fcb1[g];
#pragma unroll
        for (int j = 0; j < 64; ++j) a += b2[j] * fcW1[j * 32 + g];
        bcs[g] = a;
    }
    __syncthreads();

    float p32[32];
    float inv = 1.0f / fmaxf(gcnt[g], 1.0f);
    {
        const float4* gs4 = (const float4*)(gsum + g * 32);
#pragma unroll
        for (int q = 0; q < 8; ++q) {
            float4 v = gs4[q];
            p32[q * 4 + 0] = v.x * inv;
            p32[q * 4 + 1] = v.y * inv;
            p32[q * 4 + 2] = v.z * inv;
            p32[q * 4 + 3] = v.w * inv;
        }
    }
#pragma unroll 4
    for (int ch = 0; ch < 32; ++ch) {
        float acc = bcs[ch];
#pragma unroll
        for (int k = 0; k < 32; ++k) acc += p32[k] * wcs[k * 32 + ch];
        zs[g][ch] = fmaxf(acc, 0.f);
    }
    __syncthreads();

    {
        int ch = g & 31, seg = g >> 5;
        float s = 0.f, sq = 0.f;
#pragma unroll
        for (int i = 0; i < 32; ++i) {
            float v = zs[seg * 32 + i][ch];
            s += v;
            sq += v * v;
        }
        part1[seg][ch] = s;
        part2[seg][ch] = sq;
    }
    __syncthreads();
    if (g < 32) {
        float s = 0.f, sq = 0.f;
#pragma unroll
        for (int i = 0; i < 8; ++i) { s += part1[i][g]; sq += part2[i][g]; }
        float m = s / NG;
        float v = sq / NG - m * m;
        mu[g] = m;
        rstd[g] = rsqrtf(fmaxf(v, 0.f) + 1e-5f);
    }
    __syncthreads();

    float acc = fcb2[0];
#pragma unroll 4
    for (int ch = 0; ch < 32; ++ch) {
        float zn = (zs[g][ch] - mu[ch]) * rstd[ch] * gamma[ch] + beta[ch];
        acc += zn * fcW2[ch];
    }
    out[g] = fmaxf(acc, 0.f) + log1pf(expf(-fabsf(acc)));
}

extern "C" void kernel_launch(void* const* d_in, const int* in_sizes, int n_in,
                              void* d_out, int out_size, void* d_ws, size_t ws_size,
                              hipStream_t stream) {
    const float* x     = (const float*)d_in[0];
    const int*   ei    = (const int*)d_in[1];
    const int*   batch = (const int*)d_in[2];
    const float* W1    = (const float*)d_in[3];
    const float* b1    = (const float*)d_in[4];
    const float* W2    = (const float*)d_in[5];
    const float* b2    = (const float*)d_in[6];
    const float* fcW1  = (const float*)d_in[7];
    const float* fcb1  = (const float*)d_in[8];
    const float* gamma = (const float*)d_in[9];
    const float* beta  = (const float*)d_in[10];
    const float* fcW2  = (const float*)d_in[11];
    const float* fcb2  = (const float*)d_in[12];
    float* out = (float*)d_out;

    // workspace layout (16B aligned; bkt_cur|gsum|gcnt contiguous -> ONE memset)
    char* p = (char*)d_ws;
    int*   bkt_cur = (int*)p;        p += 400 * 4;
    float* gsum    = (float*)p;      p += (size_t)NG * 32 * 4;
    float* gcnt    = (float*)p;      p += (size_t)NG * 4;
    float* deg_inv = (float*)p;      p += (size_t)NN * 4;
    int*   row_beg = (int*)p;        p += (size_t)(NN + 8) * 4;
    int*   row_deg = (int*)p;        p += (size_t)(NN + 8) * 4;
    int*   epack   = (int*)p;        p += (size_t)NBKT * STRIDE * 4;
    int*   col     = (int*)p;        p += (size_t)NBKT * STRIDE * 4;
    unsigned short* h1s = (unsigned short*)p;  p += (size_t)(NN + 1) * 32 * 2;  // bf16 (+dummy row)
    uint2*          t1  = (uint2*)p;           p += (size_t)(NN + 1) * 8 * 8;   // bf16x4/lane (+dummy row)

    const int* srcv = ei;
    const int* dstv = ei + NE;

    (void)hipMemsetAsync(bkt_cur, 0, 400 * 4 + (size_t)NG * 32 * 4 + (size_t)NG * 4, stream);

    // CSR build: partition into fixed-stride regions -> per-bucket build
    part_kernel<<<NB_P1, 1024, 0, stream>>>(srcv, dstv, bkt_cur, epack);
    build_kernel<<<NBKT, 512, 0, stream>>>(epack, bkt_cur, row_beg, row_deg, col, deg_inv);

    // layer 1: h1s(bf16) = (x@W1)*deg_inv ; conv1 -> t1(bf16)
    gemm_x_w1<<<NN / 32, 256, 0, stream>>>(x, W1, deg_inv, h1s, NN);
    conv_bf_kernel<0><<<((size_t)NN * 8 + 511) / 512, 512, 0, stream>>>(
        row_beg, row_deg, col, (const uint2*)h1s, deg_inv, b1, t1, nullptr, nullptr, nullptr);

    // layer 2 aggregation (W2 folded into head) + fused mean-pooling
    conv_bf_kernel<1><<<((size_t)NN * 8 + 511) / 512, 512, 0, stream>>>(
        row_beg, row_deg, col, (const uint2*)t1, deg_inv, b1, nullptr, batch, gsum, gcnt);

    // head
    head_kernel<<<1, 256, 0, stream>>>(gsum, gcnt, W2, b2, fcW1, fcb1, gamma, beta, fcW2, fcb2, out);
}